// Round 6
// baseline (398.572 us; speedup 1.0000x reference)
//
#include <hip/hip_runtime.h>
#include <hip/hip_bf16.h>

#define HIDC 64
#define NPB 8          // nodes per block in k_xh
#define NEG_SLOPE 0.2f

typedef __hip_bfloat16 bf16;

static __device__ __forceinline__ float b2f(bf16 v) { return __bfloat162float(v); }

static __device__ __forceinline__ unsigned short f2us(float f) {
  bf16 b = __float2bfloat16(f);
  union { bf16 b; unsigned short u; } c;
  c.b = b;
  return c.u;
}

// dtype-specialized loads
template <bool FF>
static __device__ __forceinline__ float ld(const void* __restrict__ p, size_t i) {
  return FF ? ((const float*)p)[i] : b2f(((const bf16*)p)[i]);
}
static __device__ __forceinline__ float ldr(const void* __restrict__ p, size_t i,
                                            bool ff) {
  return ff ? ((const float*)p)[i] : b2f(((const bf16*)p)[i]);
}
template <bool I64>
static __device__ __forceinline__ int ldi(const int* __restrict__ p, long long i) {
  return I64 ? (int)((const long long*)p)[i] : p[i];
}
static __device__ __forceinline__ int clampN(int v, int N) {
  return ((unsigned)v < (unsigned)N) ? v : 0;
}

// Per-wave local dtype detection (1 load + ballot; uniform across waves since
// every wave samples the same 32 words).
static __device__ __forceinline__ bool det_f32(const unsigned* __restrict__ hw) {
  unsigned w = hw[threadIdx.x & 31];
  int ex = (w >> 7) & 0xFF;
  unsigned long long b = __ballot(ex >= 99 && ex <= 135);
  return __popcll(b) < 32;  // true => fp32 inputs
}
static __device__ __forceinline__ bool det_i64(const int* __restrict__ ei) {
  int v = ei[2 * (threadIdx.x & 31) + 1];
  return __ballot(v != 0) == 0ULL;  // true => int64 layout
}

// ---------------- fused x-GEMM + logits + in-degree histogram ----------------
template <bool FF, bool I64>
static __device__ __forceinline__ void xh_body(
    const void* __restrict__ h, const void* __restrict__ W,
    const void* __restrict__ att_src, const void* __restrict__ att_dst,
    const int* __restrict__ ei, bf16* __restrict__ x,
    float* __restrict__ a_src, float* __restrict__ a_dst,
    int* __restrict__ cnt, int N, int E) {
  {  // histogram chunk (fire-and-forget atomics overlap the GEMM below)
    int e = blockIdx.x * 256 + threadIdx.x;
    if (e < E) {
      int dst = clampN(ldi<I64>(ei, (long long)E + e), N);
      atomicAdd(&cnt[dst], 1);
    }
  }
  __shared__ float hs[NPB][HIDC];
  const int j = threadIdx.x;
  const int n0 = blockIdx.x * NPB;
  {  // vectorized h staging: one "unit" = 2 channels (uint for bf16, float2 for f32)
    int m = j >> 5, pp = j & 31;
    int n = n0 + m;
    float2 val;
    if (n < N) {
      if (FF) {
        val = ((const float2*)h)[(size_t)n0 * 32 + j];
      } else {
        unsigned u = ((const unsigned*)h)[(size_t)n0 * 32 + j];
        val.x = __uint_as_float(u << 16);
        val.y = __uint_as_float(u & 0xffff0000u);
      }
    } else {
      val.x = 0.f; val.y = 0.f;
    }
    ((float2*)&hs[m][0])[pp] = val;
  }
  __syncthreads();
  float acc[NPB];
#pragma unroll
  for (int m = 0; m < NPB; m++) acc[m] = 0.f;
  for (int k = 0; k < HIDC; k++) {
    float wk = ld<FF>(W, (size_t)k * 256 + j);
#pragma unroll
    for (int m = 0; m < NPB; m++) acc[m] += hs[m][k] * wk;
  }
  const float asj = ld<FF>(att_src, j);
  const float adj = ld<FF>(att_dst, j);
  const int lane = j & 63;
  const int head = j >> 6;
#pragma unroll
  for (int m = 0; m < NPB; m++) {
    int n = n0 + m;
    if (n >= N) break;
    x[(size_t)n * 256 + j] = __float2bfloat16(acc[m]);
    float s = acc[m] * asj;
    float d = acc[m] * adj;
#pragma unroll
    for (int off = 32; off; off >>= 1) {
      s += __shfl_down(s, off);
      d += __shfl_down(d, off);
    }
    if (lane == 0) {
      a_src[n * 4 + head] = s;
      a_dst[n * 4 + head] = d;
    }
  }
}

__global__ void __launch_bounds__(256) k_xh(
    const void* __restrict__ h, const void* __restrict__ W,
    const void* __restrict__ att_src, const void* __restrict__ att_dst,
    const int* __restrict__ ei, bf16* __restrict__ x,
    float* __restrict__ a_src, float* __restrict__ a_dst,
    int* __restrict__ cnt, int N, int E) {
  bool f32 = det_f32((const unsigned*)h);
  bool i64 = det_i64(ei);
  if (f32) {
    if (i64) xh_body<true, true>(h, W, att_src, att_dst, ei, x, a_src, a_dst, cnt, N, E);
    else     xh_body<true, false>(h, W, att_src, att_dst, ei, x, a_src, a_dst, cnt, N, E);
  } else {
    if (i64) xh_body<false, true>(h, W, att_src, att_dst, ei, x, a_src, a_dst, cnt, N, E);
    else     xh_body<false, false>(h, W, att_src, att_dst, ei, x, a_src, a_dst, cnt, N, E);
  }
}

// ---------------- single-block: M precompute + exclusive scan ----------------
__global__ void __launch_bounds__(1024) k_scanM(
    const void* __restrict__ W_edge, const void* __restrict__ att_edge,
    const unsigned* __restrict__ hw, const int* __restrict__ cnt,
    int* __restrict__ offs, int* __restrict__ cursor, float* __restrict__ M,
    int N) {
  int t = threadIdx.x;
  bool ff = det_f32(hw);
  if (t < 768) {
    int wv = t >> 6, lane = t & 63;
    int d = wv >> 2, hh = wv & 3;
    float p = ldr(W_edge, (size_t)d * 256 + hh * 64 + lane, ff) *
              ldr(att_edge, (size_t)hh * 64 + lane, ff);
#pragma unroll
    for (int o = 32; o; o >>= 1) p += __shfl_down(p, o);
    if (lane == 0) M[d * 4 + hh] = p;
  }
  __shared__ int ts[1024];
  int chunk = (N + 1023) >> 10;
  int b0 = t * chunk;
  int b1 = min(b0 + chunk, N);
  int s = 0;
  for (int i = b0; i < b1; i++) s += cnt[i];
  ts[t] = s;
  __syncthreads();
  for (int off = 1; off < 1024; off <<= 1) {
    int v = (t >= off) ? ts[t - off] : 0;
    __syncthreads();
    ts[t] += v;
    __syncthreads();
  }
  int run = (t == 0) ? 0 : ts[t - 1];
  for (int i = b0; i < b1; i++) {
    offs[i] = run;
    cursor[i] = run;
    run += cnt[i];
  }
  if (t == 1023) offs[N] = ts[1023];
}

// ---------------- fused edge weights + CSR scatter (one 16B slot) ------------
// slot = {src:int, w0|w1 (2xbf16), w2|w3 (2xbf16), 0}
template <bool FF, bool I64>
static __device__ __forceinline__ void es_body(
    const int* __restrict__ ei, const void* __restrict__ eattr,
    const float* __restrict__ a_src, const float* __restrict__ a_dst,
    const float* __restrict__ M, int* __restrict__ cursor,
    int4* __restrict__ slots, int E, int N) {
  int e = blockIdx.x * 256 + threadIdx.x;
  if (e >= E) return;
  int src = clampN(ldi<I64>(ei, e), N);
  int dst = clampN(ldi<I64>(ei, (long long)E + e), N);
  float ea0 = ld<FF>(eattr, (size_t)e * 3 + 0);
  float ea1 = ld<FF>(eattr, (size_t)e * 3 + 1);
  float ea2 = ld<FF>(eattr, (size_t)e * 3 + 2);
  const float4 m0 = ((const float4*)M)[0];
  const float4 m1 = ((const float4*)M)[1];
  const float4 m2 = ((const float4*)M)[2];
  const float4 as4 = ((const float4*)a_src)[src];
  const float4 ad4 = ((const float4*)a_dst)[dst];
  float al[4];
  al[0] = as4.x + ad4.x + ea0 * m0.x + ea1 * m1.x + ea2 * m2.x;
  al[1] = as4.y + ad4.y + ea0 * m0.y + ea1 * m1.y + ea2 * m2.y;
  al[2] = as4.z + ad4.z + ea0 * m0.z + ea1 * m1.z + ea2 * m2.z;
  al[3] = as4.w + ad4.w + ea0 * m0.w + ea1 * m1.w + ea2 * m2.w;
  unsigned short u[4];
#pragma unroll
  for (int hh = 0; hh < 4; hh++) {
    float a = al[hh];
    a = (a > 0.f) ? a : NEG_SLOPE * a;
    a = fminf(fmaxf(a, -60.f), 60.f);   // belt-and-braces; |alpha| <~ 12
    u[hh] = f2us(__expf(a));
  }
  int pos = atomicAdd(&cursor[dst], 1);
  slots[pos] = make_int4(src, (int)(u[0] | ((unsigned)u[1] << 16)),
                         (int)(u[2] | ((unsigned)u[3] << 16)), 0);
}

__global__ void __launch_bounds__(256) k_es(
    const int* __restrict__ ei, const void* __restrict__ eattr,
    const float* __restrict__ a_src, const float* __restrict__ a_dst,
    const float* __restrict__ M, const unsigned* __restrict__ hw,
    int* __restrict__ cursor, int4* __restrict__ slots, int E, int N) {
  bool f32 = det_f32(hw);
  bool i64 = det_i64(ei);
  if (f32) {
    if (i64) es_body<true, true>(ei, eattr, a_src, a_dst, M, cursor, slots, E, N);
    else     es_body<true, false>(ei, eattr, a_src, a_dst, M, cursor, slots, E, N);
  } else {
    if (i64) es_body<false, true>(ei, eattr, a_src, a_dst, M, cursor, slots, E, N);
    else     es_body<false, false>(ei, eattr, a_src, a_dst, M, cursor, slots, E, N);
  }
}

// ---------------- aggregation + head-mean + LayerNorm + SiLU -----------------
// 2 nodes per block; wave = 2 heads (128 channels), lane = channel-pair dword.
// Per edge per wave: 1 slot broadcast, 1 coalesced 256B x-load, ~13 VALU.
template <bool HZ>  // false: heads 0,1 from q.y; true: heads 2,3 from q.z
static __device__ __forceinline__ void agg_loop(
    const int4* __restrict__ slots, const unsigned* __restrict__ xw,
    int s0, int s1, bool hi_half, float& a0o, float& a1o, float& wso) {
  float a0 = 0.f, a1 = 0.f, ws = 0.f;
  int i = s0;
  for (; i + 4 <= s1; i += 4) {
    int4 q0 = slots[i], q1 = slots[i + 1], q2 = slots[i + 2], q3 = slots[i + 3];
    unsigned d0 = xw[(size_t)((unsigned)q0.x << 7)];
    unsigned d1 = xw[(size_t)((unsigned)q1.x << 7)];
    unsigned d2 = xw[(size_t)((unsigned)q2.x << 7)];
    unsigned d3 = xw[(size_t)((unsigned)q3.x << 7)];
    unsigned p0 = HZ ? (unsigned)q0.z : (unsigned)q0.y;
    unsigned p1 = HZ ? (unsigned)q1.z : (unsigned)q1.y;
    unsigned p2 = HZ ? (unsigned)q2.z : (unsigned)q2.y;
    unsigned p3 = HZ ? (unsigned)q3.z : (unsigned)q3.y;
    float w0 = __uint_as_float(hi_half ? (p0 & 0xffff0000u) : (p0 << 16));
    float w1 = __uint_as_float(hi_half ? (p1 & 0xffff0000u) : (p1 << 16));
    float w2 = __uint_as_float(hi_half ? (p2 & 0xffff0000u) : (p2 << 16));
    float w3 = __uint_as_float(hi_half ? (p3 & 0xffff0000u) : (p3 << 16));
    a0 += w0 * __uint_as_float(d0 << 16);
    a1 += w0 * __uint_as_float(d0 & 0xffff0000u);
    a0 += w1 * __uint_as_float(d1 << 16);
    a1 += w1 * __uint_as_float(d1 & 0xffff0000u);
    a0 += w2 * __uint_as_float(d2 << 16);
    a1 += w2 * __uint_as_float(d2 & 0xffff0000u);
    a0 += w3 * __uint_as_float(d3 << 16);
    a1 += w3 * __uint_as_float(d3 & 0xffff0000u);
    ws += (w0 + w1) + (w2 + w3);
  }
  for (; i < s1; i++) {
    int4 q = slots[i];
    unsigned d = xw[(size_t)((unsigned)q.x << 7)];
    unsigned pz = HZ ? (unsigned)q.z : (unsigned)q.y;
    float wv = __uint_as_float(hi_half ? (pz & 0xffff0000u) : (pz << 16));
    a0 += wv * __uint_as_float(d << 16);
    a1 += wv * __uint_as_float(d & 0xffff0000u);
    ws += wv;
  }
  a0o = a0; a1o = a1; wso = ws;
}

__global__ void __launch_bounds__(256) k_agg(
    const int* __restrict__ offs, const int4* __restrict__ slots,
    const unsigned* __restrict__ xu, const unsigned* __restrict__ hw,
    const void* __restrict__ bias, const void* __restrict__ gamma,
    const void* __restrict__ beta, void* __restrict__ out, int N) {
  __shared__ float sh[2][256];
  int t = threadIdx.x;
  int w = t >> 6, lane = t & 63;
  int nl = w >> 1;            // node slot within block
  int hb2 = w & 1;            // 0 => heads 0,1 ; 1 => heads 2,3
  int n = blockIdx.x * 2 + nl;
  if (n < N) {
    const unsigned* xw = xu + hb2 * 64 + lane;  // dword base within row
    int s0 = offs[n], s1 = offs[n + 1];
    bool hi_half = lane >= 32;
    float a0, a1, ws;
    if (hb2) agg_loop<true>(slots, xw, s0, s1, hi_half, a0, a1, ws);
    else     agg_loop<false>(slots, xw, s0, s1, hi_half, a0, a1, ws);
    float inv = 1.f / (ws + 1e-16f);
    int head = hb2 * 2 + (hi_half ? 1 : 0);
    int pidx = lane & 31;
    sh[nl][head * 64 + 2 * pidx] = a0 * inv;
    sh[nl][head * 64 + 2 * pidx + 1] = a1 * inv;
  }
  __syncthreads();
  if ((t & 127) < 64) {       // waves 0 and 2: full waves, one node each
    int nl2 = t >> 7;
    int n2 = blockIdx.x * 2 + nl2;
    if (n2 < N) {
      int c = t & 63;
      bool ff = det_f32(hw);
      float m = (sh[nl2][c] + sh[nl2][64 + c] + sh[nl2][128 + c] +
                 sh[nl2][192 + c]) * 0.25f + ldr(bias, c, ff);
      float mu = m;
#pragma unroll
      for (int off = 32; off; off >>= 1) mu += __shfl_xor(mu, off);
      mu *= (1.f / 64.f);
      float d = m - mu;
      float v = d * d;
#pragma unroll
      for (int off = 32; off; off >>= 1) v += __shfl_xor(v, off);
      v *= (1.f / 64.f);
      float y = d * rsqrtf(v + 1e-5f) * ldr(gamma, c, ff) + ldr(beta, c, ff);
      float sig = 1.f / (1.f + __expf(-y));
      float r = y * sig;
      size_t oi = (size_t)n2 * 64 + c;
      if (ff) ((float*)out)[oi] = r;
      else ((bf16*)out)[oi] = __float2bfloat16(r);
    }
  }
}

extern "C" void kernel_launch(void* const* d_in, const int* in_sizes, int n_in,
                              void* d_out, int out_size, void* d_ws,
                              size_t ws_size, hipStream_t stream) {
  const void* h        = d_in[1];
  const int*  ei       = (const int*)d_in[2];
  const void* eattr    = d_in[3];
  const void* W        = d_in[4];
  const void* att_src  = d_in[5];
  const void* att_dst  = d_in[6];
  const void* W_edge   = d_in[7];
  const void* att_edge = d_in[8];
  const void* bias     = d_in[9];
  const void* gamma    = d_in[10];
  const void* beta     = d_in[11];

  const int N = in_sizes[1] / HIDC;       // h has N*64 elements (any dtype)
  const int E = in_sizes[3] / 3;          // edge_attr has E*3 elements

  // Workspace layout (~40.6 MB), 16B-aligned segments.
  char* p = (char*)d_ws;
  float* M    = (float*)p; p += 64;                      // 12 floats
  bf16* x     = (bf16*)p;  p += (size_t)N * 256 * 2;     // 25.6 MB
  float* asrc = (float*)p; p += (size_t)N * 4 * 4;       // 0.8 MB
  float* adst = (float*)p; p += (size_t)N * 4 * 4;       // 0.8 MB
  int4* slots = (int4*)p;  p += (size_t)E * 16;          // 12.8 MB
  int* cnt    = (int*)p;   p += (size_t)N * 4;
  int* cursor = (int*)p;   p += (size_t)N * 4;
  int* offs   = (int*)p;   p += ((size_t)N + 4) * 4;

  size_t need = (size_t)(p - (char*)d_ws);
  if (ws_size < need || N <= 0 || E <= 0) {
    hipMemsetAsync(d_out, 0, (size_t)out_size * 2, stream);
    return;
  }

  hipMemsetAsync(cnt, 0, (size_t)N * 4, stream);

  k_xh<<<(N + NPB - 1) / NPB, 256, 0, stream>>>(h, W, att_src, att_dst, ei, x,
                                                asrc, adst, cnt, N, E);
  k_scanM<<<1, 1024, 0, stream>>>(W_edge, att_edge, (const unsigned*)h, cnt,
                                  offs, cursor, M, N);
  k_es<<<(E + 255) / 256, 256, 0, stream>>>(ei, eattr, asrc, adst, M,
                                            (const unsigned*)h, cursor, slots,
                                            E, N);
  k_agg<<<(N + 1) / 2, 256, 0, stream>>>(offs, slots, (const unsigned*)x,
                                         (const unsigned*)h, bias, gamma, beta,
                                         d_out, N);
}

// Round 7
// 299.243 us; speedup vs baseline: 1.3319x; 1.3319x over previous
//
#include <hip/hip_runtime.h>
#include <hip/hip_bf16.h>

#define HIDC 64
#define NPB 8          // nodes per block in k_xh
#define NEG_SLOPE 0.2f
#define SCAN_G 128     // blocks in the two-phase scan

typedef __hip_bfloat16 bf16;

static __device__ __forceinline__ float b2f(bf16 v) { return __bfloat162float(v); }

static __device__ __forceinline__ unsigned short f2us(float f) {
  bf16 b = __float2bfloat16(f);
  union { bf16 b; unsigned short u; } c;
  c.b = b;
  return c.u;
}

// dtype-specialized loads
template <bool FF>
static __device__ __forceinline__ float ld(const void* __restrict__ p, size_t i) {
  return FF ? ((const float*)p)[i] : b2f(((const bf16*)p)[i]);
}
static __device__ __forceinline__ float ldr(const void* __restrict__ p, size_t i,
                                            bool ff) {
  return ff ? ((const float*)p)[i] : b2f(((const bf16*)p)[i]);
}
template <bool I64>
static __device__ __forceinline__ int ldi(const int* __restrict__ p, long long i) {
  return I64 ? (int)((const long long*)p)[i] : p[i];
}
static __device__ __forceinline__ int clampN(int v, int N) {
  return ((unsigned)v < (unsigned)N) ? v : 0;
}

// Per-wave local dtype detection (1 load + ballot; uniform across waves since
// every wave samples the same 32 words).
static __device__ __forceinline__ bool det_f32(const unsigned* __restrict__ hw) {
  unsigned w = hw[threadIdx.x & 31];
  int ex = (w >> 7) & 0xFF;
  unsigned long long b = __ballot(ex >= 99 && ex <= 135);
  return __popcll(b) < 32;  // true => fp32 inputs
}
static __device__ __forceinline__ bool det_i64(const int* __restrict__ ei) {
  int v = ei[2 * (threadIdx.x & 31) + 1];
  return __ballot(v != 0) == 0ULL;  // true => int64 layout
}

// ---------------- fused x-GEMM + logits + in-degree histogram ----------------
template <bool FF, bool I64>
static __device__ __forceinline__ void xh_body(
    const void* __restrict__ h, const void* __restrict__ W,
    const void* __restrict__ att_src, const void* __restrict__ att_dst,
    const int* __restrict__ ei, bf16* __restrict__ x,
    float* __restrict__ a_src, float* __restrict__ a_dst,
    int* __restrict__ cnt, int N, int E) {
  {  // histogram chunk (fire-and-forget atomics overlap the GEMM below)
    int e = blockIdx.x * 256 + threadIdx.x;
    if (e < E) {
      int dst = clampN(ldi<I64>(ei, (long long)E + e), N);
      atomicAdd(&cnt[dst], 1);
    }
  }
  __shared__ float hs[NPB][HIDC];
  const int j = threadIdx.x;
  const int n0 = blockIdx.x * NPB;
  {  // vectorized h staging: one "unit" = 2 channels
    int m = j >> 5, pp = j & 31;
    int n = n0 + m;
    float2 val;
    if (n < N) {
      if (FF) {
        val = ((const float2*)h)[(size_t)n0 * 32 + j];
      } else {
        unsigned u = ((const unsigned*)h)[(size_t)n0 * 32 + j];
        val.x = __uint_as_float(u << 16);
        val.y = __uint_as_float(u & 0xffff0000u);
      }
    } else {
      val.x = 0.f; val.y = 0.f;
    }
    ((float2*)&hs[m][0])[pp] = val;
  }
  __syncthreads();
  float acc[NPB];
#pragma unroll
  for (int m = 0; m < NPB; m++) acc[m] = 0.f;
  for (int k = 0; k < HIDC; k++) {
    float wk = ld<FF>(W, (size_t)k * 256 + j);
#pragma unroll
    for (int m = 0; m < NPB; m++) acc[m] += hs[m][k] * wk;
  }
  const float asj = ld<FF>(att_src, j);
  const float adj = ld<FF>(att_dst, j);
  const int lane = j & 63;
  const int head = j >> 6;
#pragma unroll
  for (int m = 0; m < NPB; m++) {
    int n = n0 + m;
    if (n >= N) break;
    x[(size_t)n * 256 + j] = __float2bfloat16(acc[m]);
    float s = acc[m] * asj;
    float d = acc[m] * adj;
#pragma unroll
    for (int off = 32; off; off >>= 1) {
      s += __shfl_down(s, off);
      d += __shfl_down(d, off);
    }
    if (lane == 0) {
      a_src[n * 4 + head] = s;
      a_dst[n * 4 + head] = d;
    }
  }
}

__global__ void __launch_bounds__(256) k_xh(
    const void* __restrict__ h, const void* __restrict__ W,
    const void* __restrict__ att_src, const void* __restrict__ att_dst,
    const int* __restrict__ ei, bf16* __restrict__ x,
    float* __restrict__ a_src, float* __restrict__ a_dst,
    int* __restrict__ cnt, int N, int E) {
  bool f32 = det_f32((const unsigned*)h);
  bool i64 = det_i64(ei);
  if (f32) {
    if (i64) xh_body<true, true>(h, W, att_src, att_dst, ei, x, a_src, a_dst, cnt, N, E);
    else     xh_body<true, false>(h, W, att_src, att_dst, ei, x, a_src, a_dst, cnt, N, E);
  } else {
    if (i64) xh_body<false, true>(h, W, att_src, att_dst, ei, x, a_src, a_dst, cnt, N, E);
    else     xh_body<false, false>(h, W, att_src, att_dst, ei, x, a_src, a_dst, cnt, N, E);
  }
}

// ------------- scan phase 1: per-chunk local prefix + last-block bsum scan ---
// SCAN_G blocks, 1024 threads. Block b handles cnt[b*C .. b*C+C). Writes
// block-local exclusive prefix into offs, chunk total into bsum[b]
// (device-scope atomic), and the LAST block to finish scans bsum -> bbase.
// Block 0 additionally computes M[d*4+h] = sum_c W_edge[d,h*64+c]*att_edge[h,c].
__global__ void __launch_bounds__(1024) k_bscan(
    const void* __restrict__ W_edge, const void* __restrict__ att_edge,
    const unsigned* __restrict__ hw, const int* __restrict__ cnt,
    int* __restrict__ offs, int* __restrict__ bsum, int* __restrict__ bbase,
    int* __restrict__ done, float* __restrict__ M, int N) {
  int b = blockIdx.x, t = threadIdx.x;
  if (b == 0 && t < 768) {
    bool ff = det_f32(hw);
    int wv = t >> 6, lane = t & 63;
    int d = wv >> 2, hh = wv & 3;
    float p = ldr(W_edge, (size_t)d * 256 + hh * 64 + lane, ff) *
              ldr(att_edge, (size_t)hh * 64 + lane, ff);
#pragma unroll
    for (int o = 32; o; o >>= 1) p += __shfl_down(p, o);
    if (lane == 0) M[d * 4 + hh] = p;
  }
  const int C = (N + SCAN_G - 1) / SCAN_G;
  const int b0 = b * C;
  __shared__ int ts[1024];
  __shared__ int lastf;
  int v = 0;
  if (t < C && b0 + t < N) v = cnt[b0 + t];
  ts[t] = v;
  __syncthreads();
  for (int off = 1; off < 1024; off <<= 1) {
    int u = (t >= off) ? ts[t - off] : 0;
    __syncthreads();
    ts[t] += u;
    __syncthreads();
  }
  if (t < C && b0 + t < N) offs[b0 + t] = ts[t] - v;  // exclusive prefix
  if (t == 1023) {
    atomicExch(&bsum[b], ts[1023]);   // device-scope visible chunk total
    __threadfence();
    int old = atomicAdd(done, 1);
    lastf = (old == SCAN_G - 1) ? 1 : 0;
  }
  __syncthreads();
  if (lastf) {  // this block saw all other totals published
    int w = (t < SCAN_G) ? atomicAdd(&bsum[t], 0) : 0;  // atomic read
    ts[t] = w;
    __syncthreads();
    for (int off = 1; off < 1024; off <<= 1) {
      int u = (t >= off) ? ts[t - off] : 0;
      __syncthreads();
      ts[t] += u;
      __syncthreads();
    }
    if (t < SCAN_G) bbase[t] = ts[t] - w;  // exclusive block base
  }
}

// ------------- scan phase 2: add block base, emit offs + cursor --------------
__global__ void __launch_bounds__(1024) k_add(
    int* __restrict__ offs, int* __restrict__ cursor,
    const int* __restrict__ bbase, int N, int E) {
  int b = blockIdx.x, t = threadIdx.x;
  const int C = (N + SCAN_G - 1) / SCAN_G;
  const int b0 = b * C;
  int base = bbase[b];
  if (t < C && b0 + t < N) {
    int o = offs[b0 + t] + base;
    offs[b0 + t] = o;
    cursor[b0 + t] = o;
  }
  if (b == 0 && t == 0) offs[N] = E;  // every edge lands in exactly one bucket
}

// ---------------- fused edge weights + CSR scatter (one 16B slot) ------------
// slot = {src:int, w0|w1 (2xbf16), w2|w3 (2xbf16), 0}; eattr staged via LDS
// (coalesced dword loads) to avoid 3 unaligned scalar loads per thread.
template <bool FF, bool I64>
static __device__ __forceinline__ void es_body(
    const int* __restrict__ ei, const void* __restrict__ eattr,
    const float* __restrict__ a_src, const float* __restrict__ a_dst,
    const float* __restrict__ M, int* __restrict__ cursor,
    int4* __restrict__ slots, int E, int N) {
  __shared__ unsigned sattr[768];
  const long long e0 = (long long)blockIdx.x * 256;
  {  // stage this block's eattr strip: 6B/edge (bf16) or 12B/edge (f32)
    const unsigned bpe = FF ? 12u : 6u;
    const unsigned* gsrc = (const unsigned*)((const char*)eattr + e0 * bpe);
    unsigned ndw = FF ? 768u : 384u;
    // clip to end of buffer (tail block)
    long long bytes_left = ((long long)E - e0) * bpe;
    if (bytes_left < 0) bytes_left = 0;
    unsigned max_dw = (unsigned)((bytes_left + 3) >> 2);
    if (ndw > max_dw) ndw = max_dw;
    for (unsigned i = threadIdx.x; i < ndw; i += 256) sattr[i] = gsrc[i];
  }
  __syncthreads();
  long long e = e0 + threadIdx.x;
  if (e >= E) return;
  int src = clampN(ldi<I64>(ei, e), N);
  int dst = clampN(ldi<I64>(ei, (long long)E + e), N);
  float ea0, ea1, ea2;
  if (FF) {
    const float* sf = (const float*)sattr;
    ea0 = sf[threadIdx.x * 3 + 0];
    ea1 = sf[threadIdx.x * 3 + 1];
    ea2 = sf[threadIdx.x * 3 + 2];
  } else {
    const unsigned short* su = (const unsigned short*)sattr;
    ea0 = __uint_as_float((unsigned)su[threadIdx.x * 3 + 0] << 16);
    ea1 = __uint_as_float((unsigned)su[threadIdx.x * 3 + 1] << 16);
    ea2 = __uint_as_float((unsigned)su[threadIdx.x * 3 + 2] << 16);
  }
  const float4 m0 = ((const float4*)M)[0];
  const float4 m1 = ((const float4*)M)[1];
  const float4 m2 = ((const float4*)M)[2];
  const float4 as4 = ((const float4*)a_src)[src];
  const float4 ad4 = ((const float4*)a_dst)[dst];
  float al[4];
  al[0] = as4.x + ad4.x + ea0 * m0.x + ea1 * m1.x + ea2 * m2.x;
  al[1] = as4.y + ad4.y + ea0 * m0.y + ea1 * m1.y + ea2 * m2.y;
  al[2] = as4.z + ad4.z + ea0 * m0.z + ea1 * m1.z + ea2 * m2.z;
  al[3] = as4.w + ad4.w + ea0 * m0.w + ea1 * m1.w + ea2 * m2.w;
  unsigned short u[4];
#pragma unroll
  for (int hh = 0; hh < 4; hh++) {
    float a = al[hh];
    a = (a > 0.f) ? a : NEG_SLOPE * a;
    a = fminf(fmaxf(a, -60.f), 60.f);   // belt-and-braces; |alpha| <~ 12
    u[hh] = f2us(__expf(a));
  }
  int pos = atomicAdd(&cursor[dst], 1);
  slots[pos] = make_int4(src, (int)(u[0] | ((unsigned)u[1] << 16)),
                         (int)(u[2] | ((unsigned)u[3] << 16)), 0);
}

__global__ void __launch_bounds__(256) k_es(
    const int* __restrict__ ei, const void* __restrict__ eattr,
    const float* __restrict__ a_src, const float* __restrict__ a_dst,
    const float* __restrict__ M, const unsigned* __restrict__ hw,
    int* __restrict__ cursor, int4* __restrict__ slots, int E, int N) {
  bool f32 = det_f32(hw);
  bool i64 = det_i64(ei);
  if (f32) {
    if (i64) es_body<true, true>(ei, eattr, a_src, a_dst, M, cursor, slots, E, N);
    else     es_body<true, false>(ei, eattr, a_src, a_dst, M, cursor, slots, E, N);
  } else {
    if (i64) es_body<false, true>(ei, eattr, a_src, a_dst, M, cursor, slots, E, N);
    else     es_body<false, false>(ei, eattr, a_src, a_dst, M, cursor, slots, E, N);
  }
}

// ---------------- aggregation + head-mean + LayerNorm + SiLU -----------------
// 2 nodes per block; wave = 2 heads (128 channels), lane = channel-pair dword.
template <bool HZ>  // false: heads 0,1 from q.y; true: heads 2,3 from q.z
static __device__ __forceinline__ void agg_loop(
    const int4* __restrict__ slots, const unsigned* __restrict__ xw,
    int s0, int s1, bool hi_half, float& a0o, float& a1o, float& wso) {
  float a0 = 0.f, a1 = 0.f, ws = 0.f;
  int i = s0;
  for (; i + 4 <= s1; i += 4) {
    int4 q0 = slots[i], q1 = slots[i + 1], q2 = slots[i + 2], q3 = slots[i + 3];
    unsigned d0 = xw[(size_t)((unsigned)q0.x << 7)];
    unsigned d1 = xw[(size_t)((unsigned)q1.x << 7)];
    unsigned d2 = xw[(size_t)((unsigned)q2.x << 7)];
    unsigned d3 = xw[(size_t)((unsigned)q3.x << 7)];
    unsigned p0 = HZ ? (unsigned)q0.z : (unsigned)q0.y;
    unsigned p1 = HZ ? (unsigned)q1.z : (unsigned)q1.y;
    unsigned p2 = HZ ? (unsigned)q2.z : (unsigned)q2.y;
    unsigned p3 = HZ ? (unsigned)q3.z : (unsigned)q3.y;
    float w0 = __uint_as_float(hi_half ? (p0 & 0xffff0000u) : (p0 << 16));
    float w1 = __uint_as_float(hi_half ? (p1 & 0xffff0000u) : (p1 << 16));
    float w2 = __uint_as_float(hi_half ? (p2 & 0xffff0000u) : (p2 << 16));
    float w3 = __uint_as_float(hi_half ? (p3 & 0xffff0000u) : (p3 << 16));
    a0 += w0 * __uint_as_float(d0 << 16);
    a1 += w0 * __uint_as_float(d0 & 0xffff0000u);
    a0 += w1 * __uint_as_float(d1 << 16);
    a1 += w1 * __uint_as_float(d1 & 0xffff0000u);
    a0 += w2 * __uint_as_float(d2 << 16);
    a1 += w2 * __uint_as_float(d2 & 0xffff0000u);
    a0 += w3 * __uint_as_float(d3 << 16);
    a1 += w3 * __uint_as_float(d3 & 0xffff0000u);
    ws += (w0 + w1) + (w2 + w3);
  }
  for (; i < s1; i++) {
    int4 q = slots[i];
    unsigned d = xw[(size_t)((unsigned)q.x << 7)];
    unsigned pz = HZ ? (unsigned)q.z : (unsigned)q.y;
    float wv = __uint_as_float(hi_half ? (pz & 0xffff0000u) : (pz << 16));
    a0 += wv * __uint_as_float(d << 16);
    a1 += wv * __uint_as_float(d & 0xffff0000u);
    ws += wv;
  }
  a0o = a0; a1o = a1; wso = ws;
}

__global__ void __launch_bounds__(256) k_agg(
    const int* __restrict__ offs, const int4* __restrict__ slots,
    const unsigned* __restrict__ xu, const unsigned* __restrict__ hw,
    const void* __restrict__ bias, const void* __restrict__ gamma,
    const void* __restrict__ beta, void* __restrict__ out, int N) {
  __shared__ float sh[2][256];
  int t = threadIdx.x;
  int w = t >> 6, lane = t & 63;
  int nl = w >> 1;            // node slot within block
  int hb2 = w & 1;            // 0 => heads 0,1 ; 1 => heads 2,3
  int n = blockIdx.x * 2 + nl;
  if (n < N) {
    const unsigned* xw = xu + hb2 * 64 + lane;  // dword base within row
    int s0 = offs[n], s1 = offs[n + 1];
    bool hi_half = lane >= 32;
    float a0, a1, ws;
    if (hb2) agg_loop<true>(slots, xw, s0, s1, hi_half, a0, a1, ws);
    else     agg_loop<false>(slots, xw, s0, s1, hi_half, a0, a1, ws);
    float inv = 1.f / (ws + 1e-16f);
    int head = hb2 * 2 + (hi_half ? 1 : 0);
    int pidx = lane & 31;
    sh[nl][head * 64 + 2 * pidx] = a0 * inv;
    sh[nl][head * 64 + 2 * pidx + 1] = a1 * inv;
  }
  __syncthreads();
  if ((t & 127) < 64) {       // waves 0 and 2: full waves, one node each
    int nl2 = t >> 7;
    int n2 = blockIdx.x * 2 + nl2;
    if (n2 < N) {
      int c = t & 63;
      bool ff = det_f32(hw);
      float m = (sh[nl2][c] + sh[nl2][64 + c] + sh[nl2][128 + c] +
                 sh[nl2][192 + c]) * 0.25f + ldr(bias, c, ff);
      float mu = m;
#pragma unroll
      for (int off = 32; off; off >>= 1) mu += __shfl_xor(mu, off);
      mu *= (1.f / 64.f);
      float d = m - mu;
      float v = d * d;
#pragma unroll
      for (int off = 32; off; off >>= 1) v += __shfl_xor(v, off);
      v *= (1.f / 64.f);
      float y = d * rsqrtf(v + 1e-5f) * ldr(gamma, c, ff) + ldr(beta, c, ff);
      float sig = 1.f / (1.f + __expf(-y));
      float r = y * sig;
      size_t oi = (size_t)n2 * 64 + c;
      if (ff) ((float*)out)[oi] = r;
      else ((bf16*)out)[oi] = __float2bfloat16(r);
    }
  }
}

extern "C" void kernel_launch(void* const* d_in, const int* in_sizes, int n_in,
                              void* d_out, int out_size, void* d_ws,
                              size_t ws_size, hipStream_t stream) {
  const void* h        = d_in[1];
  const int*  ei       = (const int*)d_in[2];
  const void* eattr    = d_in[3];
  const void* W        = d_in[4];
  const void* att_src  = d_in[5];
  const void* att_dst  = d_in[6];
  const void* W_edge   = d_in[7];
  const void* att_edge = d_in[8];
  const void* bias     = d_in[9];
  const void* gamma    = d_in[10];
  const void* beta     = d_in[11];

  const int N = in_sizes[1] / HIDC;       // h has N*64 elements (any dtype)
  const int E = in_sizes[3] / 3;          // edge_attr has E*3 elements

  // Workspace layout (~40.7 MB), 16B-aligned segments.
  char* p = (char*)d_ws;
  float* M    = (float*)p; p += 64;                      // 12 floats
  bf16* x     = (bf16*)p;  p += (size_t)N * 256 * 2;     // 25.6 MB
  float* asrc = (float*)p; p += (size_t)N * 4 * 4;       // 0.8 MB
  float* adst = (float*)p; p += (size_t)N * 4 * 4;       // 0.8 MB
  int4* slots = (int4*)p;  p += (size_t)E * 16;          // 12.8 MB
  int* cnt    = (int*)p;   p += (size_t)N * 4;           // zeroed
  int* done   = (int*)p;   p += 64;                      // zeroed (with cnt)
  int* offs   = (int*)p;   p += ((size_t)N + 4) * 4;
  int* cursor = (int*)p;   p += (size_t)N * 4;
  int* bsum   = (int*)p;   p += SCAN_G * 4;
  int* bbase  = (int*)p;   p += SCAN_G * 4;

  size_t need = (size_t)(p - (char*)d_ws);
  if (ws_size < need || N <= 0 || E <= 0) {
    hipMemsetAsync(d_out, 0, (size_t)out_size * 2, stream);
    return;
  }

  hipMemsetAsync(cnt, 0, (size_t)N * 4 + 64, stream);  // cnt + done

  k_xh<<<(N + NPB - 1) / NPB, 256, 0, stream>>>(h, W, att_src, att_dst, ei, x,
                                                asrc, adst, cnt, N, E);
  k_bscan<<<SCAN_G, 1024, 0, stream>>>(W_edge, att_edge, (const unsigned*)h,
                                       cnt, offs, bsum, bbase, done, M, N);
  k_add<<<SCAN_G, 1024, 0, stream>>>(offs, cursor, bbase, N, E);
  k_es<<<(E + 255) / 256, 256, 0, stream>>>(ei, eattr, asrc, adst, M,
                                            (const unsigned*)h, cursor, slots,
                                            E, N);
  k_agg<<<(N + 1) / 2, 256, 0, stream>>>(offs, slots, (const unsigned*)x,
                                         (const unsigned*)h, bias, gamma, beta,
                                         d_out, N);
}

// Round 8
// 280.271 us; speedup vs baseline: 1.4221x; 1.0677x over previous
//
#include <hip/hip_runtime.h>
#include <hip/hip_bf16.h>

#define HIDC 64
#define NEG_SLOPE 0.2f
#define SCAN_G 128     // blocks in the two-phase scan

typedef __hip_bfloat16 bf16;
typedef short bf16x8 __attribute__((ext_vector_type(8)));
typedef float floatx4 __attribute__((ext_vector_type(4)));

static __device__ __forceinline__ float b2f(bf16 v) { return __bfloat162float(v); }

static __device__ __forceinline__ unsigned short f2us(float f) {
  bf16 b = __float2bfloat16(f);
  union { bf16 b; unsigned short u; } c;
  c.b = b;
  return c.u;
}

// dtype-specialized loads
template <bool FF>
static __device__ __forceinline__ float ld(const void* __restrict__ p, size_t i) {
  return FF ? ((const float*)p)[i] : b2f(((const bf16*)p)[i]);
}
static __device__ __forceinline__ float ldr(const void* __restrict__ p, size_t i,
                                            bool ff) {
  return ff ? ((const float*)p)[i] : b2f(((const bf16*)p)[i]);
}
template <bool I64>
static __device__ __forceinline__ int ldi(const int* __restrict__ p, long long i) {
  return I64 ? (int)((const long long*)p)[i] : p[i];
}
static __device__ __forceinline__ int clampN(int v, int N) {
  return ((unsigned)v < (unsigned)N) ? v : 0;
}

// Per-wave local dtype detection (1 load + ballot; uniform across waves since
// every wave samples the same 32 words).
static __device__ __forceinline__ bool det_f32(const unsigned* __restrict__ hw) {
  unsigned w = hw[threadIdx.x & 31];
  int ex = (w >> 7) & 0xFF;
  unsigned long long b = __ballot(ex >= 99 && ex <= 135);
  return __popcll(b) < 32;  // true => fp32 inputs
}
static __device__ __forceinline__ bool det_i64(const int* __restrict__ ei) {
  int v = ei[2 * (threadIdx.x & 31) + 1];
  return __ballot(v != 0) == 0ULL;  // true => int64 layout
}

// ---------------- MFMA x-GEMM + logits + in-degree histogram ----------------
// Block = 64 nodes x 256 cols. h-tile (8 KB) and W^T (32 KB) staged in LDS as
// 16B chunks of 8 k-elems, chunk q XOR-swizzled by (row&7) so that fragment
// ds_read_b128 (16 lanes, same q, rows base+0..15) is 2-way -> conflict-free.
// Wave w computes cols w*64..w*64+63 (== head w), 4 node-tiles x 4 col-tiles
// x 2 K-steps = 32 mfma_f32_16x16x32_bf16. Fragment layouts (verified, guide
// §3): A[m=lane&15][k=(lane>>4)*8+j]; B[k][n=lane&15] same k pattern;
// C/D col=lane&15, row=(lane>>4)*4+reg.
template <bool FF, bool I64>
static __device__ __forceinline__ void xh_body(
    const void* __restrict__ h, const void* __restrict__ W,
    const void* __restrict__ att_src, const void* __restrict__ att_dst,
    const int* __restrict__ ei, bf16* __restrict__ x,
    float* __restrict__ a_src, float* __restrict__ a_dst,
    int* __restrict__ cnt, int N, int E) {
  // histogram (grid-stride, fire-and-forget; overlaps staging/MFMA)
  for (long long e = (long long)blockIdx.x * 256 + threadIdx.x; e < E;
       e += (long long)gridDim.x * 256) {
    int dst = clampN(ldi<I64>(ei, (long long)E + e), N);
    atomicAdd(&cnt[dst], 1);
  }
  __shared__ alignas(16) unsigned short hls[64 * 64];    // 8 KB
  __shared__ alignas(16) unsigned short wls[256 * 64];   // 32 KB
  const int t = threadIdx.x;
  const long long n0 = (long long)blockIdx.x * 64;
  {  // stage W^T: thread t = col c; global reads coalesced per k-row
    const int c = t;
#pragma unroll
    for (int q = 0; q < 8; q++) {
      unsigned short u[8];
#pragma unroll
      for (int j = 0; j < 8; j++) {
        int k = q * 8 + j;
        u[j] = FF ? f2us(((const float*)W)[(size_t)k * 256 + c])
                  : ((const unsigned short*)W)[(size_t)k * 256 + c];
      }
      int4 v = make_int4((int)(u[0] | ((unsigned)u[1] << 16)),
                         (int)(u[2] | ((unsigned)u[3] << 16)),
                         (int)(u[4] | ((unsigned)u[5] << 16)),
                         (int)(u[6] | ((unsigned)u[7] << 16)));
      *(int4*)&wls[c * 64 + (q ^ (c & 7)) * 8] = v;
    }
  }
  {  // stage h tile: 64 rows x 8 chunks; thread -> (row=t>>2, 2 chunks)
    const int row = t >> 2;
    const long long n = n0 + row;
#pragma unroll
    for (int dq = 0; dq < 2; dq++) {
      int q = (t & 3) * 2 + dq;
      int4 v;
      if (n < N) {
        if (FF) {
          const float4* hp = (const float4*)h + n * 16 + q * 2;
          float4 f0 = hp[0], f1 = hp[1];
          v = make_int4((int)(f2us(f0.x) | ((unsigned)f2us(f0.y) << 16)),
                        (int)(f2us(f0.z) | ((unsigned)f2us(f0.w) << 16)),
                        (int)(f2us(f1.x) | ((unsigned)f2us(f1.y) << 16)),
                        (int)(f2us(f1.z) | ((unsigned)f2us(f1.w) << 16)));
        } else {
          v = *((const int4*)((const unsigned short*)h + n * 64 + q * 8));
        }
      } else {
        v = make_int4(0, 0, 0, 0);
      }
      *(int4*)&hls[row * 64 + (q ^ (row & 7)) * 8] = v;
    }
  }
  __syncthreads();
  const int w = t >> 6;          // wave = head = col group of 64
  const int lane = t & 63;
  const int lm = lane & 15, lq = lane >> 4;
  bf16x8 af[4][2];
#pragma unroll
  for (int nt = 0; nt < 4; nt++)
#pragma unroll
    for (int ks = 0; ks < 2; ks++) {
      int m = nt * 16 + lm;
      int q = ks * 4 + lq;
      af[nt][ks] = *(const bf16x8*)&hls[m * 64 + (q ^ (m & 7)) * 8];
    }
  floatx4 acc[4][4];
#pragma unroll
  for (int nt = 0; nt < 4; nt++)
#pragma unroll
    for (int ct = 0; ct < 4; ct++) acc[nt][ct] = (floatx4){0.f, 0.f, 0.f, 0.f};
#pragma unroll
  for (int ct = 0; ct < 4; ct++) {
    int c = w * 64 + ct * 16 + lm;
    bf16x8 b0 = *(const bf16x8*)&wls[c * 64 + ((lq) ^ (c & 7)) * 8];
    bf16x8 b1 = *(const bf16x8*)&wls[c * 64 + ((4 + lq) ^ (c & 7)) * 8];
#pragma unroll
    for (int nt = 0; nt < 4; nt++) {
      acc[nt][ct] = __builtin_amdgcn_mfma_f32_16x16x32_bf16(af[nt][0], b0,
                                                            acc[nt][ct], 0, 0, 0);
      acc[nt][ct] = __builtin_amdgcn_mfma_f32_16x16x32_bf16(af[nt][1], b1,
                                                            acc[nt][ct], 0, 0, 0);
    }
  }
  // epilogue: x store (bf16 scalar, lanes cover consecutive cols -> coalesced
  // 32B segments) + per-head logits via 16-lane shfl_xor reduction
  float as_c[4], ad_c[4];
#pragma unroll
  for (int ct = 0; ct < 4; ct++) {
    as_c[ct] = ld<FF>(att_src, w * 64 + ct * 16 + lm);
    ad_c[ct] = ld<FF>(att_dst, w * 64 + ct * 16 + lm);
  }
#pragma unroll
  for (int nt = 0; nt < 4; nt++) {
    float ps[4] = {0.f, 0.f, 0.f, 0.f}, pd[4] = {0.f, 0.f, 0.f, 0.f};
#pragma unroll
    for (int ct = 0; ct < 4; ct++) {
#pragma unroll
      for (int r = 0; r < 4; r++) {
        ps[r] += acc[nt][ct][r] * as_c[ct];
        pd[r] += acc[nt][ct][r] * ad_c[ct];
      }
    }
    long long nb = n0 + nt * 16 + lq * 4;
#pragma unroll
    for (int r = 0; r < 4; r++) {
      long long n = nb + r;
      if (n < N) {
#pragma unroll
        for (int ct = 0; ct < 4; ct++)
          x[n * 256 + w * 64 + ct * 16 + lm] = __float2bfloat16(acc[nt][ct][r]);
      }
    }
#pragma unroll
    for (int mask = 1; mask < 16; mask <<= 1) {
#pragma unroll
      for (int r = 0; r < 4; r++) {
        ps[r] += __shfl_xor(ps[r], mask);
        pd[r] += __shfl_xor(pd[r], mask);
      }
    }
    if (lm == 0) {
#pragma unroll
      for (int r = 0; r < 4; r++) {
        long long n = nb + r;
        if (n < N) {
          a_src[n * 4 + w] = ps[r];
          a_dst[n * 4 + w] = pd[r];
        }
      }
    }
  }
}

__global__ void __launch_bounds__(256) k_xh(
    const void* __restrict__ h, const void* __restrict__ W,
    const void* __restrict__ att_src, const void* __restrict__ att_dst,
    const int* __restrict__ ei, bf16* __restrict__ x,
    float* __restrict__ a_src, float* __restrict__ a_dst,
    int* __restrict__ cnt, int N, int E) {
  bool f32 = det_f32((const unsigned*)h);
  bool i64 = det_i64(ei);
  if (f32) {
    if (i64) xh_body<true, true>(h, W, att_src, att_dst, ei, x, a_src, a_dst, cnt, N, E);
    else     xh_body<true, false>(h, W, att_src, att_dst, ei, x, a_src, a_dst, cnt, N, E);
  } else {
    if (i64) xh_body<false, true>(h, W, att_src, att_dst, ei, x, a_src, a_dst, cnt, N, E);
    else     xh_body<false, false>(h, W, att_src, att_dst, ei, x, a_src, a_dst, cnt, N, E);
  }
}

// ------------- scan phase 1: per-chunk local prefix + last-block bsum scan ---
__global__ void __launch_bounds__(1024) k_bscan(
    const void* __restrict__ W_edge, const void* __restrict__ att_edge,
    const unsigned* __restrict__ hw, const int* __restrict__ cnt,
    int* __restrict__ offs, int* __restrict__ bsum, int* __restrict__ bbase,
    int* __restrict__ done, float* __restrict__ M, int N) {
  int b = blockIdx.x, t = threadIdx.x;
  if (b == 0 && t < 768) {
    bool ff = det_f32(hw);
    int wv = t >> 6, lane = t & 63;
    int d = wv >> 2, hh = wv & 3;
    float p = ldr(W_edge, (size_t)d * 256 + hh * 64 + lane, ff) *
              ldr(att_edge, (size_t)hh * 64 + lane, ff);
#pragma unroll
    for (int o = 32; o; o >>= 1) p += __shfl_down(p, o);
    if (lane == 0) M[d * 4 + hh] = p;
  }
  const int C = (N + SCAN_G - 1) / SCAN_G;
  const int b0 = b * C;
  __shared__ int ts[1024];
  __shared__ int lastf;
  int v = 0;
  if (t < C && b0 + t < N) v = cnt[b0 + t];
  ts[t] = v;
  __syncthreads();
  for (int off = 1; off < 1024; off <<= 1) {
    int u = (t >= off) ? ts[t - off] : 0;
    __syncthreads();
    ts[t] += u;
    __syncthreads();
  }
  if (t < C && b0 + t < N) offs[b0 + t] = ts[t] - v;  // exclusive prefix
  if (t == 1023) {
    atomicExch(&bsum[b], ts[1023]);   // device-scope visible chunk total
    __threadfence();
    int old = atomicAdd(done, 1);
    lastf = (old == SCAN_G - 1) ? 1 : 0;
  }
  __syncthreads();
  if (lastf) {  // this block saw all other totals published
    int w = (t < SCAN_G) ? atomicAdd(&bsum[t], 0) : 0;  // atomic read
    ts[t] = w;
    __syncthreads();
    for (int off = 1; off < 1024; off <<= 1) {
      int u = (t >= off) ? ts[t - off] : 0;
      __syncthreads();
      ts[t] += u;
      __syncthreads();
    }
    if (t < SCAN_G) bbase[t] = ts[t] - w;  // exclusive block base
  }
}

// ------------- scan phase 2: add block base, emit offs + cursor --------------
__global__ void __launch_bounds__(1024) k_add(
    int* __restrict__ offs, int* __restrict__ cursor,
    const int* __restrict__ bbase, int N, int E) {
  int b = blockIdx.x, t = threadIdx.x;
  const int C = (N + SCAN_G - 1) / SCAN_G;
  const int b0 = b * C;
  int base = bbase[b];
  if (t < C && b0 + t < N) {
    int o = offs[b0 + t] + base;
    offs[b0 + t] = o;
    cursor[b0 + t] = o;
  }
  if (b == 0 && t == 0) offs[N] = E;
}

// ---------------- fused edge weights + CSR scatter (one 16B slot) ------------
template <bool FF, bool I64>
static __device__ __forceinline__ void es_body(
    const int* __restrict__ ei, const void* __restrict__ eattr,
    const float* __restrict__ a_src, const float* __restrict__ a_dst,
    const float* __restrict__ M, int* __restrict__ cursor,
    int4* __restrict__ slots, int E, int N) {
  __shared__ unsigned sattr[768];
  const long long e0 = (long long)blockIdx.x * 256;
  {  // stage this block's eattr strip: 6B/edge (bf16) or 12B/edge (f32)
    const unsigned bpe = FF ? 12u : 6u;
    const unsigned* gsrc = (const unsigned*)((const char*)eattr + e0 * bpe);
    unsigned ndw = FF ? 768u : 384u;
    long long bytes_left = ((long long)E - e0) * bpe;
    if (bytes_left < 0) bytes_left = 0;
    unsigned max_dw = (unsigned)((bytes_left + 3) >> 2);
    if (ndw > max_dw) ndw = max_dw;
    for (unsigned i = threadIdx.x; i < ndw; i += 256) sattr[i] = gsrc[i];
  }
  __syncthreads();
  long long e = e0 + threadIdx.x;
  if (e >= E) return;
  int src = clampN(ldi<I64>(ei, e), N);
  int dst = clampN(ldi<I64>(ei, (long long)E + e), N);
  float ea0, ea1, ea2;
  if (FF) {
    const float* sf = (const float*)sattr;
    ea0 = sf[threadIdx.x * 3 + 0];
    ea1 = sf[threadIdx.x * 3 + 1];
    ea2 = sf[threadIdx.x * 3 + 2];
  } else {
    const unsigned short* su = (const unsigned short*)sattr;
    ea0 = __uint_as_float((unsigned)su[threadIdx.x * 3 + 0] << 16);
    ea1 = __uint_as_float((unsigned)su[threadIdx.x * 3 + 1] << 16);
    ea2 = __uint_as_float((unsigned)su[threadIdx.x * 3 + 2] << 16);
  }
  const float4 m0 = ((const float4*)M)[0];
  const float4 m1 = ((const float4*)M)[1];
  const float4 m2 = ((const float4*)M)[2];
  const float4 as4 = ((const float4*)a_src)[src];
  const float4 ad4 = ((const float4*)a_dst)[dst];
  float al[4];
  al[0] = as4.x + ad4.x + ea0 * m0.x + ea1 * m1.x + ea2 * m2.x;
  al[1] = as4.y + ad4.y + ea0 * m0.y + ea1 * m1.y + ea2 * m2.y;
  al[2] = as4.z + ad4.z + ea0 * m0.z + ea1 * m1.z + ea2 * m2.z;
  al[3] = as4.w + ad4.w + ea0 * m0.w + ea1 * m1.w + ea2 * m2.w;
  unsigned short u[4];
#pragma unroll
  for (int hh = 0; hh < 4; hh++) {
    float a = al[hh];
    a = (a > 0.f) ? a : NEG_SLOPE * a;
    a = fminf(fmaxf(a, -60.f), 60.f);
    u[hh] = f2us(__expf(a));
  }
  int pos = atomicAdd(&cursor[dst], 1);
  slots[pos] = make_int4(src, (int)(u[0] | ((unsigned)u[1] << 16)),
                         (int)(u[2] | ((unsigned)u[3] << 16)), 0);
}

__global__ void __launch_bounds__(256) k_es(
    const int* __restrict__ ei, const void* __restrict__ eattr,
    const float* __restrict__ a_src, const float* __restrict__ a_dst,
    const float* __restrict__ M, const unsigned* __restrict__ hw,
    int* __restrict__ cursor, int4* __restrict__ slots, int E, int N) {
  bool f32 = det_f32(hw);
  bool i64 = det_i64(ei);
  if (f32) {
    if (i64) es_body<true, true>(ei, eattr, a_src, a_dst, M, cursor, slots, E, N);
    else     es_body<true, false>(ei, eattr, a_src, a_dst, M, cursor, slots, E, N);
  } else {
    if (i64) es_body<false, true>(ei, eattr, a_src, a_dst, M, cursor, slots, E, N);
    else     es_body<false, false>(ei, eattr, a_src, a_dst, M, cursor, slots, E, N);
  }
}

// ---------------- aggregation + head-mean + LayerNorm + SiLU -----------------
template <bool HZ>
static __device__ __forceinline__ void agg_loop(
    const int4* __restrict__ slots, const unsigned* __restrict__ xw,
    int s0, int s1, bool hi_half, float& a0o, float& a1o, float& wso) {
  float a0 = 0.f, a1 = 0.f, ws = 0.f;
  int i = s0;
  for (; i + 4 <= s1; i += 4) {
    int4 q0 = slots[i], q1 = slots[i + 1], q2 = slots[i + 2], q3 = slots[i + 3];
    unsigned d0 = xw[(size_t)((unsigned)q0.x << 7)];
    unsigned d1 = xw[(size_t)((unsigned)q1.x << 7)];
    unsigned d2 = xw[(size_t)((unsigned)q2.x << 7)];
    unsigned d3 = xw[(size_t)((unsigned)q3.x << 7)];
    unsigned p0 = HZ ? (unsigned)q0.z : (unsigned)q0.y;
    unsigned p1 = HZ ? (unsigned)q1.z : (unsigned)q1.y;
    unsigned p2 = HZ ? (unsigned)q2.z : (unsigned)q2.y;
    unsigned p3 = HZ ? (unsigned)q3.z : (unsigned)q3.y;
    float w0 = __uint_as_float(hi_half ? (p0 & 0xffff0000u) : (p0 << 16));
    float w1 = __uint_as_float(hi_half ? (p1 & 0xffff0000u) : (p1 << 16));
    float w2 = __uint_as_float(hi_half ? (p2 & 0xffff0000u) : (p2 << 16));
    float w3 = __uint_as_float(hi_half ? (p3 & 0xffff0000u) : (p3 << 16));
    a0 += w0 * __uint_as_float(d0 << 16);
    a1 += w0 * __uint_as_float(d0 & 0xffff0000u);
    a0 += w1 * __uint_as_float(d1 << 16);
    a1 += w1 * __uint_as_float(d1 & 0xffff0000u);
    a0 += w2 * __uint_as_float(d2 << 16);
    a1 += w2 * __uint_as_float(d2 & 0xffff0000u);
    a0 += w3 * __uint_as_float(d3 << 16);
    a1 += w3 * __uint_as_float(d3 & 0xffff0000u);
    ws += (w0 + w1) + (w2 + w3);
  }
  for (; i < s1; i++) {
    int4 q = slots[i];
    unsigned d = xw[(size_t)((unsigned)q.x << 7)];
    unsigned pz = HZ ? (unsigned)q.z : (unsigned)q.y;
    float wv = __uint_as_float(hi_half ? (pz & 0xffff0000u) : (pz << 16));
    a0 += wv * __uint_as_float(d << 16);
    a1 += wv * __uint_as_float(d & 0xffff0000u);
    ws += wv;
  }
  a0o = a0; a1o = a1; wso = ws;
}

__global__ void __launch_bounds__(256) k_agg(
    const int* __restrict__ offs, const int4* __restrict__ slots,
    const unsigned* __restrict__ xu, const unsigned* __restrict__ hw,
    const void* __restrict__ bias, const void* __restrict__ gamma,
    const void* __restrict__ beta, void* __restrict__ out, int N) {
  __shared__ float sh[2][256];
  int t = threadIdx.x;
  int w = t >> 6, lane = t & 63;
  int nl = w >> 1;
  int hb2 = w & 1;
  int n = blockIdx.x * 2 + nl;
  if (n < N) {
    const unsigned* xw = xu + hb2 * 64 + lane;
    int s0 = offs[n], s1 = offs[n + 1];
    bool hi_half = lane >= 32;
    float a0, a1, ws;
    if (hb2) agg_loop<true>(slots, xw, s0, s1, hi_half, a0, a1, ws);
    else     agg_loop<false>(slots, xw, s0, s1, hi_half, a0, a1, ws);
    float inv = 1.f / (ws + 1e-16f);
    int head = hb2 * 2 + (hi_half ? 1 : 0);
    int pidx = lane & 31;
    sh[nl][head * 64 + 2 * pidx] = a0 * inv;
    sh[nl][head * 64 + 2 * pidx + 1] = a1 * inv;
  }
  __syncthreads();
  if ((t & 127) < 64) {
    int nl2 = t >> 7;
    int n2 = blockIdx.x * 2 + nl2;
    if (n2 < N) {
      int c = t & 63;
      bool ff = det_f32(hw);
      float m = (sh[nl2][c] + sh[nl2][64 + c] + sh[nl2][128 + c] +
                 sh[nl2][192 + c]) * 0.25f + ldr(bias, c, ff);
      float mu = m;
#pragma unroll
      for (int off = 32; off; off >>= 1) mu += __shfl_xor(mu, off);
      mu *= (1.f / 64.f);
      float d = m - mu;
      float v = d * d;
#pragma unroll
      for (int off = 32; off; off >>= 1) v += __shfl_xor(v, off);
      v *= (1.f / 64.f);
      float y = d * rsqrtf(v + 1e-5f) * ldr(gamma, c, ff) + ldr(beta, c, ff);
      float sig = 1.f / (1.f + __expf(-y));
      float r = y * sig;
      size_t oi = (size_t)n2 * 64 + c;
      if (ff) ((float*)out)[oi] = r;
      else ((bf16*)out)[oi] = __float2bfloat16(r);
    }
  }
}

extern "C" void kernel_launch(void* const* d_in, const int* in_sizes, int n_in,
                              void* d_out, int out_size, void* d_ws,
                              size_t ws_size, hipStream_t stream) {
  const void* h        = d_in[1];
  const int*  ei       = (const int*)d_in[2];
  const void* eattr    = d_in[3];
  const void* W        = d_in[4];
  const void* att_src  = d_in[5];
  const void* att_dst  = d_in[6];
  const void* W_edge   = d_in[7];
  const void* att_edge = d_in[8];
  const void* bias     = d_in[9];
  const void* gamma    = d_in[10];
  const void* beta     = d_in[11];

  const int N = in_sizes[1] / HIDC;       // h has N*64 elements (any dtype)
  const int E = in_sizes[3] / 3;          // edge_attr has E*3 elements

  // Workspace layout (~40.7 MB), 16B-aligned segments.
  char* p = (char*)d_ws;
  float* M    = (float*)p; p += 64;                      // 12 floats
  bf16* x     = (bf16*)p;  p += (size_t)N * 256 * 2;     // 25.6 MB
  float* asrc = (float*)p; p += (size_t)N * 4 * 4;       // 0.8 MB
  float* adst = (float*)p; p += (size_t)N * 4 * 4;       // 0.8 MB
  int4* slots = (int4*)p;  p += (size_t)E * 16;          // 12.8 MB
  int* cnt    = (int*)p;   p += (size_t)N * 4;           // zeroed
  int* done   = (int*)p;   p += 64;                      // zeroed (with cnt)
  int* offs   = (int*)p;   p += ((size_t)N + 4) * 4;
  int* cursor = (int*)p;   p += (size_t)N * 4;
  int* bsum   = (int*)p;   p += SCAN_G * 4;
  int* bbase  = (int*)p;   p += SCAN_G * 4;

  size_t need = (size_t)(p - (char*)d_ws);
  if (ws_size < need || N <= 0 || E <= 0) {
    hipMemsetAsync(d_out, 0, (size_t)out_size * 2, stream);
    return;
  }

  hipMemsetAsync(cnt, 0, (size_t)N * 4 + 64, stream);  // cnt + done

  k_xh<<<(N + 63) / 64, 256, 0, stream>>>(h, W, att_src, att_dst, ei, x,
                                          asrc, adst, cnt, N, E);
  k_bscan<<<SCAN_G, 1024, 0, stream>>>(W_edge, att_edge, (const unsigned*)h,
                                       cnt, offs, bsum, bbase, done, M, N);
  k_add<<<SCAN_G, 1024, 0, stream>>>(offs, cursor, bbase, N, E);
  k_es<<<(E + 255) / 256, 256, 0, stream>>>(ei, eattr, asrc, adst, M,
                                            (const unsigned*)h, cursor, slots,
                                            E, N);
  k_agg<<<(N + 1) / 2, 256, 0, stream>>>(offs, slots, (const unsigned*)x,
                                         (const unsigned*)h, bias, gamma, beta,
                                         d_out, N);
}

// Round 9
// 277.854 us; speedup vs baseline: 1.4345x; 1.0087x over previous
//
#include <hip/hip_runtime.h>
#include <hip/hip_bf16.h>

#define HIDC 64
#define NEG_SLOPE 0.2f
#define SCAN_G 128     // blocks in the two-phase scan

typedef __hip_bfloat16 bf16;
typedef short bf16x8 __attribute__((ext_vector_type(8)));
typedef float floatx4 __attribute__((ext_vector_type(4)));

static __device__ __forceinline__ float b2f(bf16 v) { return __bfloat162float(v); }

static __device__ __forceinline__ unsigned short f2us(float f) {
  bf16 b = __float2bfloat16(f);
  union { bf16 b; unsigned short u; } c;
  c.b = b;
  return c.u;
}

// dtype-specialized loads
template <bool FF>
static __device__ __forceinline__ float ld(const void* __restrict__ p, size_t i) {
  return FF ? ((const float*)p)[i] : b2f(((const bf16*)p)[i]);
}
static __device__ __forceinline__ float ldr(const void* __restrict__ p, size_t i,
                                            bool ff) {
  return ff ? ((const float*)p)[i] : b2f(((const bf16*)p)[i]);
}
template <bool I64>
static __device__ __forceinline__ int ldi(const int* __restrict__ p, long long i) {
  return I64 ? (int)((const long long*)p)[i] : p[i];
}
static __device__ __forceinline__ int clampN(int v, int N) {
  return ((unsigned)v < (unsigned)N) ? v : 0;
}

// Per-wave local dtype detection (1 load + ballot; uniform across waves since
// every wave samples the same 32 words).
static __device__ __forceinline__ bool det_f32(const unsigned* __restrict__ hw) {
  unsigned w = hw[threadIdx.x & 31];
  int ex = (w >> 7) & 0xFF;
  unsigned long long b = __ballot(ex >= 99 && ex <= 135);
  return __popcll(b) < 32;  // true => fp32 inputs
}
static __device__ __forceinline__ bool det_i64(const int* __restrict__ ei) {
  int v = ei[2 * (threadIdx.x & 31) + 1];
  return __ballot(v != 0) == 0ULL;  // true => int64 layout
}

// ---------------- MFMA x-GEMM + logits + in-degree histogram ----------------
// Block = 64 nodes x 256 cols. h-tile (8 KB) and W^T (32 KB) staged in LDS as
// 16B chunks of 8 k-elems, chunk q XOR-swizzled by (row&7). LDS tiles are
// DECLARED IN THE WRAPPER and passed in: declaring them in this (4x
// instantiated, inlined) body gave 4 separate copies -> 160 KB/block -> 1
// block/CU (round-8 counter: LDS_Block_Size=163840, occupancy 1.2%).
template <bool FF, bool I64>
static __device__ __forceinline__ void xh_body(
    const void* __restrict__ h, const void* __restrict__ W,
    const void* __restrict__ att_src, const void* __restrict__ att_dst,
    const int* __restrict__ ei, bf16* __restrict__ x,
    float* __restrict__ a_src, float* __restrict__ a_dst,
    int* __restrict__ cnt, int N, int E,
    unsigned short* __restrict__ hls, unsigned short* __restrict__ wls) {
  // histogram (grid-stride, fire-and-forget; overlaps staging/MFMA)
  for (long long e = (long long)blockIdx.x * 256 + threadIdx.x; e < E;
       e += (long long)gridDim.x * 256) {
    int dst = clampN(ldi<I64>(ei, (long long)E + e), N);
    atomicAdd(&cnt[dst], 1);
  }
  const int t = threadIdx.x;
  const long long n0 = (long long)blockIdx.x * 64;
  {  // stage W^T: thread t = col c; global reads coalesced per k-row
    const int c = t;
#pragma unroll
    for (int q = 0; q < 8; q++) {
      unsigned short u[8];
#pragma unroll
      for (int j = 0; j < 8; j++) {
        int k = q * 8 + j;
        u[j] = FF ? f2us(((const float*)W)[(size_t)k * 256 + c])
                  : ((const unsigned short*)W)[(size_t)k * 256 + c];
      }
      int4 v = make_int4((int)(u[0] | ((unsigned)u[1] << 16)),
                         (int)(u[2] | ((unsigned)u[3] << 16)),
                         (int)(u[4] | ((unsigned)u[5] << 16)),
                         (int)(u[6] | ((unsigned)u[7] << 16)));
      *(int4*)&wls[c * 64 + (q ^ (c & 7)) * 8] = v;
    }
  }
  {  // stage h tile: 64 rows x 8 chunks; thread -> (row=t>>2, 2 chunks)
    const int row = t >> 2;
    const long long n = n0 + row;
#pragma unroll
    for (int dq = 0; dq < 2; dq++) {
      int q = (t & 3) * 2 + dq;
      int4 v;
      if (n < N) {
        if (FF) {
          const float4* hp = (const float4*)h + n * 16 + q * 2;
          float4 f0 = hp[0], f1 = hp[1];
          v = make_int4((int)(f2us(f0.x) | ((unsigned)f2us(f0.y) << 16)),
                        (int)(f2us(f0.z) | ((unsigned)f2us(f0.w) << 16)),
                        (int)(f2us(f1.x) | ((unsigned)f2us(f1.y) << 16)),
                        (int)(f2us(f1.z) | ((unsigned)f2us(f1.w) << 16)));
        } else {
          v = *((const int4*)((const unsigned short*)h + n * 64 + q * 8));
        }
      } else {
        v = make_int4(0, 0, 0, 0);
      }
      *(int4*)&hls[row * 64 + (q ^ (row & 7)) * 8] = v;
    }
  }
  __syncthreads();
  const int w = t >> 6;          // wave = head = col group of 64
  const int lane = t & 63;
  const int lm = lane & 15, lq = lane >> 4;
  bf16x8 af[4][2];
#pragma unroll
  for (int nt = 0; nt < 4; nt++)
#pragma unroll
    for (int ks = 0; ks < 2; ks++) {
      int m = nt * 16 + lm;
      int q = ks * 4 + lq;
      af[nt][ks] = *(const bf16x8*)&hls[m * 64 + (q ^ (m & 7)) * 8];
    }
  floatx4 acc[4][4];
#pragma unroll
  for (int nt = 0; nt < 4; nt++)
#pragma unroll
    for (int ct = 0; ct < 4; ct++) acc[nt][ct] = (floatx4){0.f, 0.f, 0.f, 0.f};
#pragma unroll
  for (int ct = 0; ct < 4; ct++) {
    int c = w * 64 + ct * 16 + lm;
    bf16x8 b0 = *(const bf16x8*)&wls[c * 64 + ((lq) ^ (c & 7)) * 8];
    bf16x8 b1 = *(const bf16x8*)&wls[c * 64 + ((4 + lq) ^ (c & 7)) * 8];
#pragma unroll
    for (int nt = 0; nt < 4; nt++) {
      acc[nt][ct] = __builtin_amdgcn_mfma_f32_16x16x32_bf16(af[nt][0], b0,
                                                            acc[nt][ct], 0, 0, 0);
      acc[nt][ct] = __builtin_amdgcn_mfma_f32_16x16x32_bf16(af[nt][1], b1,
                                                            acc[nt][ct], 0, 0, 0);
    }
  }
  // epilogue: x store + per-head logits via 16-lane shfl_xor reduction
  float as_c[4], ad_c[4];
#pragma unroll
  for (int ct = 0; ct < 4; ct++) {
    as_c[ct] = ld<FF>(att_src, w * 64 + ct * 16 + lm);
    ad_c[ct] = ld<FF>(att_dst, w * 64 + ct * 16 + lm);
  }
#pragma unroll
  for (int nt = 0; nt < 4; nt++) {
    float ps[4] = {0.f, 0.f, 0.f, 0.f}, pd[4] = {0.f, 0.f, 0.f, 0.f};
#pragma unroll
    for (int ct = 0; ct < 4; ct++) {
#pragma unroll
      for (int r = 0; r < 4; r++) {
        ps[r] += acc[nt][ct][r] * as_c[ct];
        pd[r] += acc[nt][ct][r] * ad_c[ct];
      }
    }
    long long nb = n0 + nt * 16 + lq * 4;
#pragma unroll
    for (int r = 0; r < 4; r++) {
      long long n = nb + r;
      if (n < N) {
#pragma unroll
        for (int ct = 0; ct < 4; ct++)
          x[n * 256 + w * 64 + ct * 16 + lm] = __float2bfloat16(acc[nt][ct][r]);
      }
    }
#pragma unroll
    for (int mask = 1; mask < 16; mask <<= 1) {
#pragma unroll
      for (int r = 0; r < 4; r++) {
        ps[r] += __shfl_xor(ps[r], mask);
        pd[r] += __shfl_xor(pd[r], mask);
      }
    }
    if (lm == 0) {
#pragma unroll
      for (int r = 0; r < 4; r++) {
        long long n = nb + r;
        if (n < N) {
          a_src[n * 4 + w] = ps[r];
          a_dst[n * 4 + w] = pd[r];
        }
      }
    }
  }
}

__global__ void __launch_bounds__(256) k_xh(
    const void* __restrict__ h, const void* __restrict__ W,
    const void* __restrict__ att_src, const void* __restrict__ att_dst,
    const int* __restrict__ ei, bf16* __restrict__ x,
    float* __restrict__ a_src, float* __restrict__ a_dst,
    int* __restrict__ cnt, int N, int E) {
  __shared__ alignas(16) unsigned short hls[64 * 64];    // 8 KB (shared by all
  __shared__ alignas(16) unsigned short wls[256 * 64];   // 32 KB  instantiations)
  bool f32 = det_f32((const unsigned*)h);
  bool i64 = det_i64(ei);
  if (f32) {
    if (i64) xh_body<true, true>(h, W, att_src, att_dst, ei, x, a_src, a_dst, cnt, N, E, hls, wls);
    else     xh_body<true, false>(h, W, att_src, att_dst, ei, x, a_src, a_dst, cnt, N, E, hls, wls);
  } else {
    if (i64) xh_body<false, true>(h, W, att_src, att_dst, ei, x, a_src, a_dst, cnt, N, E, hls, wls);
    else     xh_body<false, false>(h, W, att_src, att_dst, ei, x, a_src, a_dst, cnt, N, E, hls, wls);
  }
}

// ------------- scan phase 1: per-chunk local prefix + last-block bsum scan ---
__global__ void __launch_bounds__(1024) k_bscan(
    const void* __restrict__ W_edge, const void* __restrict__ att_edge,
    const unsigned* __restrict__ hw, const int* __restrict__ cnt,
    int* __restrict__ offs, int* __restrict__ bsum, int* __restrict__ bbase,
    int* __restrict__ done, float* __restrict__ M, int N) {
  int b = blockIdx.x, t = threadIdx.x;
  if (b == 0 && t < 768) {
    bool ff = det_f32(hw);
    int wv = t >> 6, lane = t & 63;
    int d = wv >> 2, hh = wv & 3;
    float p = ldr(W_edge, (size_t)d * 256 + hh * 64 + lane, ff) *
              ldr(att_edge, (size_t)hh * 64 + lane, ff);
#pragma unroll
    for (int o = 32; o; o >>= 1) p += __shfl_down(p, o);
    if (lane == 0) M[d * 4 + hh] = p;
  }
  const int C = (N + SCAN_G - 1) / SCAN_G;
  const int b0 = b * C;
  __shared__ int ts[1024];
  __shared__ int lastf;
  int v = 0;
  if (t < C && b0 + t < N) v = cnt[b0 + t];
  ts[t] = v;
  __syncthreads();
  for (int off = 1; off < 1024; off <<= 1) {
    int u = (t >= off) ? ts[t - off] : 0;
    __syncthreads();
    ts[t] += u;
    __syncthreads();
  }
  if (t < C && b0 + t < N) offs[b0 + t] = ts[t] - v;  // exclusive prefix
  if (t == 1023) {
    atomicExch(&bsum[b], ts[1023]);   // device-scope visible chunk total
    __threadfence();
    int old = atomicAdd(done, 1);
    lastf = (old == SCAN_G - 1) ? 1 : 0;
  }
  __syncthreads();
  if (lastf) {  // this block saw all other totals published
    int w = (t < SCAN_G) ? atomicAdd(&bsum[t], 0) : 0;  // atomic read
    ts[t] = w;
    __syncthreads();
    for (int off = 1; off < 1024; off <<= 1) {
      int u = (t >= off) ? ts[t - off] : 0;
      __syncthreads();
      ts[t] += u;
      __syncthreads();
    }
    if (t < SCAN_G) bbase[t] = ts[t] - w;  // exclusive block base
  }
}

// ------------- scan phase 2: add block base, emit offs + cursor --------------
__global__ void __launch_bounds__(1024) k_add(
    int* __restrict__ offs, int* __restrict__ cursor,
    const int* __restrict__ bbase, int N, int E) {
  int b = blockIdx.x, t = threadIdx.x;
  const int C = (N + SCAN_G - 1) / SCAN_G;
  const int b0 = b * C;
  int base = bbase[b];
  if (t < C && b0 + t < N) {
    int o = offs[b0 + t] + base;
    offs[b0 + t] = o;
    cursor[b0 + t] = o;
  }
  if (b == 0 && t == 0) offs[N] = E;
}

// ---------------- fused edge weights + CSR scatter (one 16B slot) ------------
template <bool FF, bool I64>
static __device__ __forceinline__ void es_body(
    const int* __restrict__ ei, const void* __restrict__ eattr,
    const float* __restrict__ a_src, const float* __restrict__ a_dst,
    const float* __restrict__ M, int* __restrict__ cursor,
    int4* __restrict__ slots, int E, int N, unsigned* __restrict__ sattr) {
  const long long e0 = (long long)blockIdx.x * 256;
  {  // stage this block's eattr strip: 6B/edge (bf16) or 12B/edge (f32)
    const unsigned bpe = FF ? 12u : 6u;
    const unsigned* gsrc = (const unsigned*)((const char*)eattr + e0 * bpe);
    unsigned ndw = FF ? 768u : 384u;
    long long bytes_left = ((long long)E - e0) * bpe;
    if (bytes_left < 0) bytes_left = 0;
    unsigned max_dw = (unsigned)((bytes_left + 3) >> 2);
    if (ndw > max_dw) ndw = max_dw;
    for (unsigned i = threadIdx.x; i < ndw; i += 256) sattr[i] = gsrc[i];
  }
  __syncthreads();
  long long e = e0 + threadIdx.x;
  if (e >= E) return;
  int src = clampN(ldi<I64>(ei, e), N);
  int dst = clampN(ldi<I64>(ei, (long long)E + e), N);
  float ea0, ea1, ea2;
  if (FF) {
    const float* sf = (const float*)sattr;
    ea0 = sf[threadIdx.x * 3 + 0];
    ea1 = sf[threadIdx.x * 3 + 1];
    ea2 = sf[threadIdx.x * 3 + 2];
  } else {
    const unsigned short* su = (const unsigned short*)sattr;
    ea0 = __uint_as_float((unsigned)su[threadIdx.x * 3 + 0] << 16);
    ea1 = __uint_as_float((unsigned)su[threadIdx.x * 3 + 1] << 16);
    ea2 = __uint_as_float((unsigned)su[threadIdx.x * 3 + 2] << 16);
  }
  const float4 m0 = ((const float4*)M)[0];
  const float4 m1 = ((const float4*)M)[1];
  const float4 m2 = ((const float4*)M)[2];
  const float4 as4 = ((const float4*)a_src)[src];
  const float4 ad4 = ((const float4*)a_dst)[dst];
  float al[4];
  al[0] = as4.x + ad4.x + ea0 * m0.x + ea1 * m1.x + ea2 * m2.x;
  al[1] = as4.y + ad4.y + ea0 * m0.y + ea1 * m1.y + ea2 * m2.y;
  al[2] = as4.z + ad4.z + ea0 * m0.z + ea1 * m1.z + ea2 * m2.z;
  al[3] = as4.w + ad4.w + ea0 * m0.w + ea1 * m1.w + ea2 * m2.w;
  unsigned short u[4];
#pragma unroll
  for (int hh = 0; hh < 4; hh++) {
    float a = al[hh];
    a = (a > 0.f) ? a : NEG_SLOPE * a;
    a = fminf(fmaxf(a, -60.f), 60.f);
    u[hh] = f2us(__expf(a));
  }
  int pos = atomicAdd(&cursor[dst], 1);
  slots[pos] = make_int4(src, (int)(u[0] | ((unsigned)u[1] << 16)),
                         (int)(u[2] | ((unsigned)u[3] << 16)), 0);
}

__global__ void __launch_bounds__(256) k_es(
    const int* __restrict__ ei, const void* __restrict__ eattr,
    const float* __restrict__ a_src, const float* __restrict__ a_dst,
    const float* __restrict__ M, const unsigned* __restrict__ hw,
    int* __restrict__ cursor, int4* __restrict__ slots, int E, int N) {
  __shared__ unsigned sattr[768];
  bool f32 = det_f32(hw);
  bool i64 = det_i64(ei);
  if (f32) {
    if (i64) es_body<true, true>(ei, eattr, a_src, a_dst, M, cursor, slots, E, N, sattr);
    else     es_body<true, false>(ei, eattr, a_src, a_dst, M, cursor, slots, E, N, sattr);
  } else {
    if (i64) es_body<false, true>(ei, eattr, a_src, a_dst, M, cursor, slots, E, N, sattr);
    else     es_body<false, false>(ei, eattr, a_src, a_dst, M, cursor, slots, E, N, sattr);
  }
}

// ---------------- aggregation + head-mean + LayerNorm + SiLU -----------------
template <bool HZ>
static __device__ __forceinline__ void agg_loop(
    const int4* __restrict__ slots, const unsigned* __restrict__ xw,
    int s0, int s1, bool hi_half, float& a0o, float& a1o, float& wso) {
  float a0 = 0.f, a1 = 0.f, ws = 0.f;
  int i = s0;
  for (; i + 4 <= s1; i += 4) {
    int4 q0 = slots[i], q1 = slots[i + 1], q2 = slots[i + 2], q3 = slots[i + 3];
    unsigned d0 = xw[(size_t)((unsigned)q0.x << 7)];
    unsigned d1 = xw[(size_t)((unsigned)q1.x << 7)];
    unsigned d2 = xw[(size_t)((unsigned)q2.x << 7)];
    unsigned d3 = xw[(size_t)((unsigned)q3.x << 7)];
    unsigned p0 = HZ ? (unsigned)q0.z : (unsigned)q0.y;
    unsigned p1 = HZ ? (unsigned)q1.z : (unsigned)q1.y;
    unsigned p2 = HZ ? (unsigned)q2.z : (unsigned)q2.y;
    unsigned p3 = HZ ? (unsigned)q3.z : (unsigned)q3.y;
    float w0 = __uint_as_float(hi_half ? (p0 & 0xffff0000u) : (p0 << 16));
    float w1 = __uint_as_float(hi_half ? (p1 & 0xffff0000u) : (p1 << 16));
    float w2 = __uint_as_float(hi_half ? (p2 & 0xffff0000u) : (p2 << 16));
    float w3 = __uint_as_float(hi_half ? (p3 & 0xffff0000u) : (p3 << 16));
    a0 += w0 * __uint_as_float(d0 << 16);
    a1 += w0 * __uint_as_float(d0 & 0xffff0000u);
    a0 += w1 * __uint_as_float(d1 << 16);
    a1 += w1 * __uint_as_float(d1 & 0xffff0000u);
    a0 += w2 * __uint_as_float(d2 << 16);
    a1 += w2 * __uint_as_float(d2 & 0xffff0000u);
    a0 += w3 * __uint_as_float(d3 << 16);
    a1 += w3 * __uint_as_float(d3 & 0xffff0000u);
    ws += (w0 + w1) + (w2 + w3);
  }
  for (; i < s1; i++) {
    int4 q = slots[i];
    unsigned d = xw[(size_t)((unsigned)q.x << 7)];
    unsigned pz = HZ ? (unsigned)q.z : (unsigned)q.y;
    float wv = __uint_as_float(hi_half ? (pz & 0xffff0000u) : (pz << 16));
    a0 += wv * __uint_as_float(d << 16);
    a1 += wv * __uint_as_float(d & 0xffff0000u);
    ws += wv;
  }
  a0o = a0; a1o = a1; wso = ws;
}

__global__ void __launch_bounds__(256) k_agg(
    const int* __restrict__ offs, const int4* __restrict__ slots,
    const unsigned* __restrict__ xu, const unsigned* __restrict__ hw,
    const void* __restrict__ bias, const void* __restrict__ gamma,
    const void* __restrict__ beta, void* __restrict__ out, int N) {
  __shared__ float sh[2][256];
  int t = threadIdx.x;
  int w = t >> 6, lane = t & 63;
  int nl = w >> 1;
  int hb2 = w & 1;
  int n = blockIdx.x * 2 + nl;
  if (n < N) {
    const unsigned* xw = xu + hb2 * 64 + lane;
    int s0 = offs[n], s1 = offs[n + 1];
    bool hi_half = lane >= 32;
    float a0, a1, ws;
    if (hb2) agg_loop<true>(slots, xw, s0, s1, hi_half, a0, a1, ws);
    else     agg_loop<false>(slots, xw, s0, s1, hi_half, a0, a1, ws);
    float inv = 1.f / (ws + 1e-16f);
    int head = hb2 * 2 + (hi_half ? 1 : 0);
    int pidx = lane & 31;
    sh[nl][head * 64 + 2 * pidx] = a0 * inv;
    sh[nl][head * 64 + 2 * pidx + 1] = a1 * inv;
  }
  __syncthreads();
  if ((t & 127) < 64) {
    int nl2 = t >> 7;
    int n2 = blockIdx.x * 2 + nl2;
    if (n2 < N) {
      int c = t & 63;
      bool ff = det_f32(hw);
      float m = (sh[nl2][c] + sh[nl2][64 + c] + sh[nl2][128 + c] +
                 sh[nl2][192 + c]) * 0.25f + ldr(bias, c, ff);
      float mu = m;
#pragma unroll
      for (int off = 32; off; off >>= 1) mu += __shfl_xor(mu, off);
      mu *= (1.f / 64.f);
      float d = m - mu;
      float v = d * d;
#pragma unroll
      for (int off = 32; off; off >>= 1) v += __shfl_xor(v, off);
      v *= (1.f / 64.f);
      float y = d * rsqrtf(v + 1e-5f) * ldr(gamma, c, ff) + ldr(beta, c, ff);
      float sig = 1.f / (1.f + __expf(-y));
      float r = y * sig;
      size_t oi = (size_t)n2 * 64 + c;
      if (ff) ((float*)out)[oi] = r;
      else ((bf16*)out)[oi] = __float2bfloat16(r);
    }
  }
}

extern "C" void kernel_launch(void* const* d_in, const int* in_sizes, int n_in,
                              void* d_out, int out_size, void* d_ws,
                              size_t ws_size, hipStream_t stream) {
  const void* h        = d_in[1];
  const int*  ei       = (const int*)d_in[2];
  const void* eattr    = d_in[3];
  const void* W        = d_in[4];
  const void* att_src  = d_in[5];
  const void* att_dst  = d_in[6];
  const void* W_edge   = d_in[7];
  const void* att_edge = d_in[8];
  const void* bias     = d_in[9];
  const void* gamma    = d_in[10];
  const void* beta     = d_in[11];

  const int N = in_sizes[1] / HIDC;       // h has N*64 elements (any dtype)
  const int E = in_sizes[3] / 3;          // edge_attr has E*3 elements

  // Workspace layout (~40.7 MB), 16B-aligned segments.
  char* p = (char*)d_ws;
  float* M    = (float*)p; p += 64;                      // 12 floats
  bf16* x     = (bf16*)p;  p += (size_t)N * 256 * 2;     // 25.6 MB
  float* asrc = (float*)p; p += (size_t)N * 4 * 4;       // 0.8 MB
  float* adst = (float*)p; p += (size_t)N * 4 * 4;       // 0.8 MB
  int4* slots = (int4*)p;  p += (size_t)E * 16;          // 12.8 MB
  int* cnt    = (int*)p;   p += (size_t)N * 4;           // zeroed
  int* done   = (int*)p;   p += 64;                      // zeroed (with cnt)
  int* offs   = (int*)p;   p += ((size_t)N + 4) * 4;
  int* cursor = (int*)p;   p += (size_t)N * 4;
  int* bsum   = (int*)p;   p += SCAN_G * 4;
  int* bbase  = (int*)p;   p += SCAN_G * 4;

  size_t need = (size_t)(p - (char*)d_ws);
  if (ws_size < need || N <= 0 || E <= 0) {
    hipMemsetAsync(d_out, 0, (size_t)out_size * 2, stream);
    return;
  }

  hipMemsetAsync(cnt, 0, (size_t)N * 4 + 64, stream);  // cnt + done

  k_xh<<<(N + 63) / 64, 256, 0, stream>>>(h, W, att_src, att_dst, ei, x,
                                          asrc, adst, cnt, N, E);
  k_bscan<<<SCAN_G, 1024, 0, stream>>>(W_edge, att_edge, (const unsigned*)h,
                                       cnt, offs, bsum, bbase, done, M, N);
  k_add<<<SCAN_G, 1024, 0, stream>>>(offs, cursor, bbase, N, E);
  k_es<<<(E + 255) / 256, 256, 0, stream>>>(ei, eattr, asrc, adst, M,
                                            (const unsigned*)h, cursor, slots,
                                            E, N);
  k_agg<<<(N + 1) / 2, 256, 0, stream>>>(offs, slots, (const unsigned*)x,
                                         (const unsigned*)h, bias, gamma, beta,
                                         d_out, N);
}